// Round 5
// baseline (457.925 us; speedup 1.0000x reference)
//
#include <hip/hip_runtime.h>
#include <cstddef>

// Problem constants
constexpr int Bn  = 512;
constexpr int Dd  = 960;
constexpr int RL  = 16;
constexpr int RD  = 32;
constexpr int LPp = 16;
constexpr int LHh = 384;
constexpr int DP  = 358;
constexpr int DH  = 154;
constexpr int SEGH  = 96;   // H l-segment length
constexpr int NSEGH = 4;    // segments per H batch

typedef float f32x4 __attribute__((ext_vector_type(4)));

// =====================================================================
// K1 vseg: V_part[b,seg][p][d] = sum_{l in seg, l<len} A[l][p] * X[b][l][d]
// Work unit = (batch, 96-row l-segment): 2048 H + 512 P = 2560 blocks,
// ~2.5x oversubscribed vs residency -> HW backfill absorbs the len skew
// (the round-3 fused kernel's 249us was the per-CU sum-of-len tail).
// No LDS; 64 f32 accumulators; len forced to SGPR so A-row loads stay
// scalar (s_load) and VGPR count stays ~<100 (no spill, 5 blocks/CU).
// Dead segments (seg*96 >= len) exit before streaming; K2 never reads them.
// =====================================================================
__global__ __launch_bounds__(256)
void vseg_kernel(const float* __restrict__ XH, const int* __restrict__ mH,
                 const float* __restrict__ AH, float* __restrict__ VH,
                 const float* __restrict__ XP, const int* __restrict__ mP,
                 const float* __restrict__ AP, float* __restrict__ VP)
{
    const int id = blockIdx.x;
    const float* X; const int* mask; const float* A; float* V;
    int L, l0, seglen, b;
    if (id < Bn * NSEGH) {
        b = id >> 2; const int seg = id & 3;
        X = XH; mask = mH; A = AH;
        V = VH + (size_t)(b * NSEGH + seg) * RL * Dd;
        L = LHh; l0 = seg * SEGH; seglen = SEGH;
    } else {
        b = id - Bn * NSEGH;
        X = XP; mask = mP; A = AP;
        V = VP + (size_t)b * RL * Dd;
        L = LPp; l0 = 0; seglen = LPp;
    }
    const int t = threadIdx.x;

    // len = popcount of contiguous-prefix mask row
    __shared__ int s_len;
    if (t == 0) s_len = 0;
    __syncthreads();
    int loc = 0;
    for (int i = t; i < L; i += 256) loc += mask[(size_t)b * L + i];
    if (loc) atomicAdd(&s_len, loc);
    __syncthreads();
    const int len = __builtin_amdgcn_readfirstlane(s_len);

    if (l0 >= len) return;          // dead segment: K2 skips it
    if (t >= 240) return;           // 240 threads x 4 d-cols = 960
    const int l1 = min(len, l0 + seglen);

    float v[RL][4];
    #pragma unroll
    for (int p = 0; p < RL; ++p)
        #pragma unroll
        for (int q = 0; q < 4; ++q) v[p][q] = 0.f;

    const float* xrow = X + ((size_t)b * L + l0) * Dd + 4 * t;
    for (int l = l0; l < l1; ++l) {
        f32x4 xv = __builtin_nontemporal_load((const f32x4*)xrow);
        xrow += Dd;
        float a[RL];
        *(f32x4*)&a[0]  = *(const f32x4*)(A + (size_t)l * RL + 0);
        *(f32x4*)&a[4]  = *(const f32x4*)(A + (size_t)l * RL + 4);
        *(f32x4*)&a[8]  = *(const f32x4*)(A + (size_t)l * RL + 8);
        *(f32x4*)&a[12] = *(const f32x4*)(A + (size_t)l * RL + 12);
        #pragma unroll
        for (int p = 0; p < RL; ++p) {
            v[p][0] = fmaf(a[p], xv[0], v[p][0]);
            v[p][1] = fmaf(a[p], xv[1], v[p][1]);
            v[p][2] = fmaf(a[p], xv[2], v[p][2]);
            v[p][3] = fmaf(a[p], xv[3], v[p][3]);
        }
    }
    #pragma unroll
    for (int p = 0; p < RL; ++p)
        *(f32x4*)(V + (size_t)p * Dd + 4 * t) = *(f32x4*)&v[p][0];
}

// =====================================================================
// K2 tail: per batch, fused U -> z -> MLP1 -> MLP2 -> concat out.
//   U[p][r] = sum_d (sum_segs V_part[p][d]) * Bc[d][r]   (Ush, 2KB LDS)
//   z[j]    = sum_i Ush[i] * Hc[i][j]                    (zs LDS)
//   h       = relu(bn(z @ W1 + b1))                      (hs LDS)
//   out[b, ooff+c] = h @ W2 + b2
// Only ~5KB LDS -> high occupancy; weights are L2-resident; V-partial
// sum done before the Bc multiply so Bc lines are read once per d.
// =====================================================================
struct TailP {
    const int*   mask;
    const float* V;     // partial base: (B, max_segs, 16, 960)
    const float* Bc;    // (960, 32)
    const float* Hc;    // (512, dmod)
    const float* W1; const float* b1; const float* g; const float* beta;
    const float* W2; const float* b2;
    int L, dmod, ooff, max_segs, seglen;
};

__global__ __launch_bounds__(256)
void tail_kernel(TailP H, TailP P, float* __restrict__ out)
{
    const bool isH = (blockIdx.x & 1);
    const TailP E = isH ? H : P;
    const int b = blockIdx.x >> 1;
    const int t = threadIdx.x;

    __shared__ float Ush[RL * RD];
    __shared__ float zs[DP];
    __shared__ float hs[DP];
    __shared__ int   s_len;

    if (t == 0) s_len = 0;
    __syncthreads();
    int loc = 0;
    for (int i = t; i < E.L; i += 256) loc += E.mask[(size_t)b * E.L + i];
    if (loc) atomicAdd(&s_len, loc);
    __syncthreads();
    const int len  = __builtin_amdgcn_readfirstlane(s_len);
    const int nseg = min(E.max_segs, (len + E.seglen - 1) / E.seglen);

    // ---- U phase ----
    const float* Vb = E.V + (size_t)b * E.max_segs * RL * Dd;
    const int p = t >> 5, r = t & 31;
    float u0 = 0.f, u1 = 0.f;
    for (int d = 0; d < Dd; d += 4) {
        f32x4 a0 = {0.f, 0.f, 0.f, 0.f}, a1 = {0.f, 0.f, 0.f, 0.f};
        for (int s = 0; s < nseg; ++s) {
            a0 += *(const f32x4*)(Vb + ((size_t)s * RL + p) * Dd + d);
            a1 += *(const f32x4*)(Vb + ((size_t)s * RL + p + 8) * Dd + d);
        }
        #pragma unroll
        for (int q = 0; q < 4; ++q) {
            float bc = E.Bc[(size_t)(d + q) * RD + r];
            u0 = fmaf(a0[q], bc, u0);
            u1 = fmaf(a1[q], bc, u1);
        }
    }
    Ush[p * RD + r]       = u0;
    Ush[(p + 8) * RD + r] = u1;
    __syncthreads();

    // ---- z phase ----
    for (int j = t; j < E.dmod; j += 256) {
        float acc = 0.f;
        #pragma unroll 8
        for (int i = 0; i < RL * RD; ++i)
            acc = fmaf(Ush[i], E.Hc[(size_t)i * E.dmod + j], acc);
        zs[j] = acc;
    }
    __syncthreads();

    // ---- MLP layer 1 + BN + ReLU ----
    const float bscale = rsqrtf(1.f + 1e-5f);
    for (int c = t; c < E.dmod; c += 256) {
        float acc = E.b1[c];
        #pragma unroll 4
        for (int k = 0; k < E.dmod; ++k)
            acc = fmaf(zs[k], E.W1[(size_t)k * E.dmod + c], acc);
        acc = fmaf(acc, E.g[c] * bscale, E.beta[c]);
        hs[c] = fmaxf(acc, 0.f);
    }
    __syncthreads();

    // ---- MLP layer 2 + concat store ----
    for (int c = t; c < E.dmod; c += 256) {
        float acc = E.b2[c];
        #pragma unroll 4
        for (int k = 0; k < E.dmod; ++k)
            acc = fmaf(hs[k], E.W2[(size_t)k * E.dmod + c], acc);
        out[(size_t)b * (DP + DH) + E.ooff + c] = acc;
    }
}

// =====================================================================
extern "C" void kernel_launch(void* const* d_in, const int* in_sizes, int n_in,
                              void* d_out, int out_size, void* d_ws, size_t ws_size,
                              hipStream_t stream)
{
    const float* emb_P  = (const float*)d_in[0];
    const float* emb_H  = (const float*)d_in[1];
    const int*   mask_P = (const int*)  d_in[2];
    const int*   mask_H = (const int*)  d_in[3];
    const float* B_cP   = (const float*)d_in[4];
    const float* A_cP   = (const float*)d_in[5];
    const float* H_cP   = (const float*)d_in[6];
    const float* W1P    = (const float*)d_in[7];
    const float* b1P    = (const float*)d_in[8];
    const float* gP     = (const float*)d_in[9];
    const float* betaP  = (const float*)d_in[10];
    const float* W2P    = (const float*)d_in[11];
    const float* b2P    = (const float*)d_in[12];
    const float* B_cH   = (const float*)d_in[13];
    const float* A_cH   = (const float*)d_in[14];
    const float* H_cH   = (const float*)d_in[15];
    const float* W1H    = (const float*)d_in[16];
    const float* b1H    = (const float*)d_in[17];
    const float* gH     = (const float*)d_in[18];
    const float* betaH  = (const float*)d_in[19];
    const float* W2H    = (const float*)d_in[20];
    const float* b2H    = (const float*)d_in[21];
    float* outp = (float*)d_out;

    // workspace layout (floats)
    float* ws  = (float*)d_ws;
    float* V_H = ws;                                      // 512*4*16*960
    float* V_P = V_H + (size_t)Bn * NSEGH * RL * Dd;      // 512*16*960

    dim3 blk(256);

    // K1: V partials, over-decomposed for load balance
    vseg_kernel<<<dim3(Bn * NSEGH + Bn), blk, 0, stream>>>(
        emb_H, mask_H, A_cH, V_H,
        emb_P, mask_P, A_cP, V_P);

    // K2: per-batch fused tail (H/P interleaved)
    TailP H, P;
    H.mask = mask_H; H.V = V_H; H.Bc = B_cH; H.Hc = H_cH;
    H.W1 = W1H; H.b1 = b1H; H.g = gH; H.beta = betaH; H.W2 = W2H; H.b2 = b2H;
    H.L = LHh; H.dmod = DH; H.ooff = DP; H.max_segs = NSEGH; H.seglen = SEGH;

    P.mask = mask_P; P.V = V_P; P.Bc = B_cP; P.Hc = H_cP;
    P.W1 = W1P; P.b1 = b1P; P.g = gP; P.beta = betaP; P.W2 = W2P; P.b2 = b2P;
    P.L = LPp; P.dmod = DP; P.ooff = 0; P.max_segs = 1; P.seglen = LPp;

    tail_kernel<<<dim3(2 * Bn), blk, 0, stream>>>(H, P, outp);
}